// Round 1
// baseline (476.694 us; speedup 1.0000x reference)
//
#include <hip/hip_runtime.h>
#include <stdint.h>

typedef unsigned long long u64;
typedef unsigned int u32;

#define SCAT_TILE 2048   // items per histogram/scatter block (256 thr * 8)
#define SUF_TILE  4096   // items per suffix-scan block      (256 thr * 16)

// ---------------- block-level primitives ----------------

__device__ __forceinline__ u32 blk_exscan_u32(u32 v) {
  __shared__ u32 sh[256];
  u32 t = threadIdx.x;
  sh[t] = v; __syncthreads();
  for (u32 o = 1; o < 256; o <<= 1) {
    u32 x = (t >= o) ? sh[t - o] : 0u;
    __syncthreads();
    sh[t] += x;
    __syncthreads();
  }
  u32 inc = sh[t];
  __syncthreads();
  return inc - v;
}

__device__ __forceinline__ double blk_exscan_f64(double v) {
  __shared__ double sh[256];
  u32 t = threadIdx.x;
  sh[t] = v; __syncthreads();
  for (u32 o = 1; o < 256; o <<= 1) {
    double x = (t >= o) ? sh[t - o] : 0.0;
    __syncthreads();
    sh[t] += x;
    __syncthreads();
  }
  double inc = sh[t];
  __syncthreads();
  return inc - v;
}

__device__ __forceinline__ double blk_reduce_f64(double v) {
  __shared__ double sh[4];
  #pragma unroll
  for (int o = 32; o > 0; o >>= 1) v += __shfl_down(v, (unsigned)o, 64);
  u32 lane = threadIdx.x & 63u, w = threadIdx.x >> 6;
  __syncthreads();
  if (lane == 0) sh[w] = v;
  __syncthreads();
  return sh[0] + sh[1] + sh[2] + sh[3];
}

// ---------------- kernel 1: fused MSE partials + sort-item build ----------------
// item = (~bits(target[:,0]) << 32) | bits(pred[:,0])
// ascending sort on high dword == stable descending sort of target (== argsort(-t))

__global__ void fuse_k(const float* __restrict__ pred, const float* __restrict__ tgt,
                       u64* __restrict__ items, double* __restrict__ part3, int N) {
  int i = blockIdx.x * 256 + threadIdx.x;   // row index
  float comp = 0.f, rm = 0.f, ss = 0.f;
  if (i < N) {
    float4 p0 = ((const float4*)pred)[i * 2];
    float4 p1 = ((const float4*)pred)[i * 2 + 1];
    float4 t0 = ((const float4*)tgt)[i * 2];
    float4 t1 = ((const float4*)tgt)[i * 2 + 1];
    float d0 = p0.x - t0.x; comp = d0 * d0;
    float d1 = p0.y - t0.y, d2 = p0.z - t0.z, d3 = p0.w - t0.w;
    float d4 = p1.x - t1.x, d5 = p1.y - t1.y, d6 = p1.z - t1.z, d7 = p1.w - t1.w;
    rm = d1*d1 + d2*d2 + d3*d3 + d4*d4 + d5*d5 + d6*d6 + d7*d7;
    ss = p0.x;
    u32 key = ~__float_as_uint(t0.x);
    items[i] = ((u64)key << 32) | (u64)__float_as_uint(p0.x);
  }
  double c = blk_reduce_f64((double)comp);
  double r = blk_reduce_f64((double)rm);
  double s = blk_reduce_f64((double)ss);
  if (threadIdx.x == 0) {
    part3[blockIdx.x * 3 + 0] = c;
    part3[blockIdx.x * 3 + 1] = r;
    part3[blockIdx.x * 3 + 2] = s;
  }
}

// ---------------- radix sort: histogram ----------------

__global__ void hist_k(const u64* __restrict__ src, u32* __restrict__ counts,
                       int shift, int nblk) {
  __shared__ u32 h[256];
  u32 t = threadIdx.x;
  h[t] = 0; __syncthreads();
  int base = blockIdx.x * SCAT_TILE;
  #pragma unroll
  for (int j = 0; j < SCAT_TILE / 256; j++) {
    u32 key = ((const u32*)src)[2 * (base + j * 256 + t) + 1];
    atomicAdd(&h[(key >> shift) & 255u], 1u);
  }
  __syncthreads();
  counts[t * nblk + blockIdx.x] = h[t];  // digit-major layout
}

// per-digit exclusive scan over blocks (grid = 256, one block per digit)
__global__ void scanA_k(u32* __restrict__ counts, u32* __restrict__ digit_total, int nblk) {
  int d = blockIdx.x; u32 t = threadIdx.x;
  int nper = nblk / 256;
  u32 base = (u32)d * (u32)nblk + t * (u32)nper;
  u32 v[16]; u32 s = 0;
  for (int k = 0; k < nper; k++) { v[k] = counts[base + k]; s += v[k]; }
  u32 ex = blk_exscan_u32(s);
  u32 run = ex;
  for (int k = 0; k < nper; k++) { u32 c = v[k]; counts[base + k] = run; run += c; }
  if (t == 255) digit_total[d] = run;
}

// exclusive scan over the 256 digit totals
__global__ void scanB_k(const u32* __restrict__ digit_total, u32* __restrict__ digit_base) {
  u32 t = threadIdx.x;
  digit_base[t] = blk_exscan_u32(digit_total[t]);
}

// ---------------- radix sort: stable LDS-staged scatter ----------------

template <bool LAST>
__global__ __launch_bounds__(256) void scatter_k(
    const u64* __restrict__ src, u64* __restrict__ dst, float* __restrict__ dstf,
    const u32* __restrict__ counts, const u32* __restrict__ digit_base,
    int shift, int nblk) {
  __shared__ u32 sh_glob[256];
  __shared__ u32 sh_run[256];
  __shared__ u32 sh_cnt[4][256];
  __shared__ u32 sh_start[256];
  __shared__ u64 sh_items[SCAT_TILE];
  u32 t = threadIdx.x, wave = t >> 6, lane = t & 63u;
  u32 blk = blockIdx.x;
  sh_glob[t] = digit_base[t] + counts[t * (u32)nblk + blk];
  sh_run[t] = 0;
  u64 it[8]; u32 dg[8]; u32 lp[8];
  int base = blk * SCAT_TILE;
  #pragma unroll
  for (int j = 0; j < 8; j++) {
    it[j] = src[base + j * 256 + (int)t];
    dg[j] = (u32)(it[j] >> (32 + shift)) & 255u;
  }
  __syncthreads();
  // stable local ranking: element order = (j, wave, lane) == ascending global idx
  #pragma unroll
  for (int j = 0; j < 8; j++) {
    sh_cnt[0][t] = 0; sh_cnt[1][t] = 0; sh_cnt[2][t] = 0; sh_cnt[3][t] = 0;
    __syncthreads();
    u32 dd = dg[j];
    u64 m = ~0ull;
    #pragma unroll
    for (int b = 0; b < 8; b++) {
      u64 vb = __ballot((int)((dd >> b) & 1u));
      m &= ((dd >> b) & 1u) ? vb : ~vb;
    }
    u32 rank = (u32)__popcll(m & ((1ull << lane) - 1ull));
    if (rank == 0) sh_cnt[wave][dd] = (u32)__popcll(m);
    __syncthreads();
    u32 off = sh_run[dd] + rank;
    for (u32 w = 0; w < wave; w++) off += sh_cnt[w][dd];
    lp[j] = off;
    u32 s4 = sh_cnt[0][t] + sh_cnt[1][t] + sh_cnt[2][t] + sh_cnt[3][t];
    __syncthreads();
    sh_run[t] += s4;   // visible to next iteration after its post-zero barrier
  }
  __syncthreads();
  u32 st = blk_exscan_u32(sh_run[t]);
  sh_start[t] = st;
  __syncthreads();
  #pragma unroll
  for (int j = 0; j < 8; j++) sh_items[sh_start[dg[j]] + lp[j]] = it[j];
  __syncthreads();
  #pragma unroll
  for (int j = 0; j < 8; j++) {
    u32 p = (u32)j * 256u + t;
    u64 item = sh_items[p];
    u32 dd = (u32)(item >> (32 + shift)) & 255u;
    u32 gpos = sh_glob[dd] + (p - sh_start[dd]);
    if (LAST) dstf[gpos] = __uint_as_float((u32)(item & 0xFFFFFFFFull));
    else      dst[gpos] = item;
  }
}

// ---------------- suffix log-sum-exp ----------------

__global__ void expsum_k(const float* __restrict__ s, double* __restrict__ bsum) {
  u32 t = threadIdx.x, blk = blockIdx.x;
  const float4* q = (const float4*)(s + blk * SUF_TILE + t * 16);
  double a = 0.0;
  #pragma unroll
  for (int k = 0; k < 4; k++) {
    float4 v = q[k];
    a += (double)expf(v.x) + (double)expf(v.y) + (double)expf(v.z) + (double)expf(v.w);
  }
  double r = blk_reduce_f64(a);
  if (t == 0) bsum[blk] = r;
}

__global__ void sufscan_k(const double* __restrict__ bsum, double* __restrict__ bsuf, int nsb) {
  u32 t = threadIdx.x;
  int nper = nsb / 256;
  double v[8]; double s = 0.0;
  for (int k = 0; k < nper; k++) { v[k] = bsum[t * (u32)nper + k]; s += v[k]; }
  double ex = blk_exscan_f64(s);
  __shared__ double tot;
  if (t == 255) tot = ex + s;
  __syncthreads();
  double run = ex;
  for (int k = 0; k < nper; k++) { bsuf[t * (u32)nper + k] = tot - run - v[k]; run += v[k]; }
}

__global__ void logsuf_k(const float* __restrict__ s, const double* __restrict__ bsuf,
                         double* __restrict__ partialL) {
  u32 t = threadIdx.x, blk = blockIdx.x;
  const float4* q = (const float4*)(s + blk * SUF_TILE + t * 16);
  float e[16];
  #pragma unroll
  for (int k = 0; k < 4; k++) {
    float4 v = q[k];
    e[4*k+0] = expf(v.x); e[4*k+1] = expf(v.y); e[4*k+2] = expf(v.z); e[4*k+3] = expf(v.w);
  }
  double rs = 0.0;
  #pragma unroll
  for (int k = 0; k < 16; k++) rs += (double)e[k];
  double ex = blk_exscan_f64(rs);
  __shared__ double tot;
  if (t == 255) tot = ex + rs;
  __syncthreads();
  double base = bsuf[blk] + (tot - ex - rs);   // suffix sum strictly after this run
  double T = base;
  double lacc = 0.0;
  #pragma unroll
  for (int k = 15; k >= 0; k--) { T += (double)e[k]; lacc += (double)logf((float)T); }
  double r = blk_reduce_f64(lacc);
  if (t == 0) partialL[blk] = r;
}

// ---------------- finalize ----------------

__global__ void finalize_k(const double* __restrict__ part3, int n3,
                           const double* __restrict__ partialL, int nL,
                           float* __restrict__ out, double invN, double invRN) {
  u32 t = threadIdx.x;
  double c = 0, r = 0, s = 0, L = 0;
  for (int b = t; b < n3; b += 256) {
    c += part3[3 * b]; r += part3[3 * b + 1]; s += part3[3 * b + 2];
  }
  for (int b = t; b < nL; b += 256) L += partialL[b];
  c = blk_reduce_f64(c);
  r = blk_reduce_f64(r);
  s = blk_reduce_f64(s);
  L = blk_reduce_f64(L);
  if (t == 0) {
    double total = c * invN + 0.5 * (r * invRN) + 0.3 * ((L - s) * invN);
    out[0] = (float)total;
  }
}

// ---------------- host launch ----------------

extern "C" void kernel_launch(void* const* d_in, const int* in_sizes, int n_in,
                              void* d_out, int out_size, void* d_ws, size_t ws_size,
                              hipStream_t stream) {
  const float* pred = (const float*)d_in[0];
  const float* tgt  = (const float*)d_in[1];
  float* out = (float*)d_out;
  int N = in_sizes[0] / 8;            // rows (4,194,304)

  int NFB = (N + 255) / 256;          // fuse blocks        (16384)
  int NB  = N / SCAT_TILE;            // radix blocks       (2048)
  int NSB = N / SUF_TILE;             // suffix-scan blocks (1024)

  char* ws = (char*)d_ws;
  size_t off = 0;
  auto alloc = [&](size_t bytes) -> char* {
    char* p = ws + off;
    off = (off + bytes + 255) & ~(size_t)255;
    return p;
  };
  double* part3    = (double*)alloc((size_t)NFB * 3 * sizeof(double));
  double* partialL = (double*)alloc((size_t)NSB * sizeof(double));
  double* bsum     = (double*)alloc((size_t)NSB * sizeof(double));
  double* bsuf     = (double*)alloc((size_t)NSB * sizeof(double));
  u32* digit_total = (u32*)alloc(256 * sizeof(u32));
  u32* digit_base  = (u32*)alloc(256 * sizeof(u32));
  u32* counts      = (u32*)alloc((size_t)256 * NB * sizeof(u32));
  u64* itemsA      = (u64*)alloc((size_t)N * sizeof(u64));
  u64* itemsB      = (u64*)alloc((size_t)N * sizeof(u64));
  float* sortedS   = (float*)itemsA;  // final pass writes floats into A region (src is B)

  fuse_k<<<NFB, 256, 0, stream>>>(pred, tgt, itemsA, part3, N);

  const u64* src = itemsA;
  u64* dst = itemsB;
  for (int pass = 0; pass < 4; ++pass) {
    int shift = pass * 8;
    hist_k<<<NB, 256, 0, stream>>>(src, counts, shift, NB);
    scanA_k<<<256, 256, 0, stream>>>(counts, digit_total, NB);
    scanB_k<<<1, 256, 0, stream>>>(digit_total, digit_base);
    if (pass < 3) {
      scatter_k<false><<<NB, 256, 0, stream>>>(src, dst, (float*)nullptr,
                                               counts, digit_base, shift, NB);
      const u64* tmp = src; src = dst; dst = (u64*)tmp;
    } else {
      scatter_k<true><<<NB, 256, 0, stream>>>(src, (u64*)nullptr, sortedS,
                                              counts, digit_base, shift, NB);
    }
  }

  expsum_k<<<NSB, 256, 0, stream>>>(sortedS, bsum);
  sufscan_k<<<1, 256, 0, stream>>>(bsum, bsuf, NSB);
  logsuf_k<<<NSB, 256, 0, stream>>>(sortedS, bsuf, partialL);
  finalize_k<<<1, 256, 0, stream>>>(part3, NFB, partialL, NSB, out,
                                    1.0 / (double)N, 1.0 / ((double)N * 7.0));
}